// Round 19
// baseline (176.139 us; speedup 1.0000x reference)
//
#include <hip/hip_runtime.h>
#include <hip/hip_bf16.h>
#include <math.h>

static constexpr int H = 480, W = 320, NH = 24, NW = 16, NB = 384;
static constexpr int HW = H * W;            // 153600
static constexpr int H2 = 240, W2 = 160;
static constexpr int HW2 = H2 * W2;         // 38400
static constexpr int H4 = 120, W4 = 80;
static constexpr int HW4 = H4 * W4;         // 9600
static constexpr int IMG_PIX = 3 * 1920 * 1280;  // 7372800

typedef __attribute__((ext_vector_type(8))) short short8;
typedef __attribute__((ext_vector_type(4))) float f32x4;
typedef __attribute__((ext_vector_type(8))) unsigned short ushort8;

// fragment-major packed weights: each chunk = 512 shorts = [lane(64)][8],
// lane = (kq<<4)|col holds w[co = nt*16+col][ci = kc*32 + kq*8 + j].
// A wave's B-fragment load is ONE contiguous 1KB read (16 cache lines).
static constexpr int WQ_CX2 = 0;          // 72 chunks: (t*2+kc)*4+nt
static constexpr int WQ_CX3 = 36864;      // 54 chunks: (t*2+kc)*3+nt
static constexpr int WQ_LT2 = 64512;      // 27 chunks: t*3+nt (ci>=16 zero)
static constexpr int WQ_FCX = 78336;      // 4 chunks: nt (k>=27 zero)
static constexpr int WQ_FLT = 80384;      // 1 chunk
static constexpr int WQ_CLS2 = 80896;     // 54 chunks: (pl*9+t)*2+nt
static constexpr int WPK_ALL = 108544;

__device__ __forceinline__ int iclamp(int v, int lo, int hi) {
    return v < lo ? lo : (v > hi ? hi : v);
}
__device__ __forceinline__ unsigned short f2bfu(float x) {
    __hip_bfloat16 h = __float2bfloat16(x);
    return *reinterpret_cast<unsigned short*>(&h);
}
__device__ __forceinline__ float bf2f(unsigned short u) {
    __hip_bfloat16 h = *reinterpret_cast<__hip_bfloat16*>(&u);
    return __bfloat162float(h);
}

// ---------------- weight pre-pack (fragment-major) ----------------

__global__ __launch_bounds__(256) void k_pack(const float* __restrict__ cx_w2,
                                              const float* __restrict__ cx_w3,
                                              const float* __restrict__ lt_w2,
                                              const float* __restrict__ cx_w1,
                                              const float* __restrict__ lt_w1,
                                              const float* __restrict__ cls_w2,
                                              unsigned short* __restrict__ wpk) {
    int i = blockIdx.x * 256 + threadIdx.x;
    if (i >= WPK_ALL) return;
    float v = 0.f;
    if (i < WQ_CX3) {
        int c = i >> 9, r = i & 511;
        int lane = r >> 3, j = r & 7;
        int col = lane & 15, kq = lane >> 4;
        int nt = c & 3, kc = (c >> 2) & 1, t = c >> 3;
        int co = nt * 16 + col, ci = kc * 32 + kq * 8 + j;
        v = cx_w2[(co * 64 + ci) * 9 + t];
    } else if (i < WQ_LT2) {
        int c = (i - WQ_CX3) >> 9, r = i & 511;
        int lane = r >> 3, j = r & 7;
        int col = lane & 15, kq = lane >> 4;
        int nt = c % 3, q = c / 3;
        int kc = q & 1, t = q >> 1;
        int co = nt * 16 + col, ci = kc * 32 + kq * 8 + j;
        v = cx_w3[(co * 64 + ci) * 9 + t];
    } else if (i < WQ_FCX) {
        int c = (i - WQ_LT2) >> 9, r = i & 511;
        int lane = r >> 3, j = r & 7;
        int col = lane & 15, kq = lane >> 4;
        int nt = c % 3, t = c / 3;
        int co = nt * 16 + col, ci = kq * 8 + j;
        v = (ci < 16) ? lt_w2[(co * 16 + ci) * 9 + t] : 0.f;
    } else if (i < WQ_FLT) {
        int c = (i - WQ_FCX) >> 9, r = i & 511;
        int lane = r >> 3, j = r & 7;
        int col = lane & 15, kq = lane >> 4;
        int co = c * 16 + col, k = kq * 8 + j;
        v = (k < 27) ? cx_w1[co * 27 + k] : 0.f;
    } else if (i < WQ_CLS2) {
        int r = i & 511;
        int lane = r >> 3, j = r & 7;
        int col = lane & 15, kq = lane >> 4;
        int k = kq * 8 + j;
        v = (k < 27) ? lt_w1[col * 27 + k] : 0.f;
    } else {
        int c = (i - WQ_CLS2) >> 9, r = i & 511;
        int lane = r >> 3, j = r & 7;
        int col = lane & 15, kq = lane >> 4;
        int nt = c & 1, q = c >> 1;
        int t = q % 9, pl = q / 9;
        int co = nt * 16 + col, ci = kq * 8 + j;
        float w = cls_w2[(co * 32 + ci) * 9 + t];
        unsigned short h = f2bfu(w);
        float r1 = w - bf2f(h);
        unsigned short m = f2bfu(r1);
        unsigned short l = f2bfu(r1 - bf2f(m));
        wpk[i] = pl == 0 ? h : (pl == 1 ? m : l);
        return;
    }
    wpk[i] = f2bfu(v);
}

// ---------------- classifier ----------------

__global__ __launch_bounds__(256) void k_cls1s(const float* __restrict__ x,
                                               const float* __restrict__ w,
                                               const float* __restrict__ b,
                                               unsigned short* __restrict__ c1s) {
    int p = blockIdx.x * 256 + threadIdx.x;
    if (p >= HW) return;
    int coc = blockIdx.y;  // 0..3
    int y = p / W, xx = p - y * W;
    float in[27];
#pragma unroll
    for (int ci = 0; ci < 3; ++ci)
#pragma unroll
        for (int dy = 0; dy < 3; ++dy) {
            int yy = iclamp(y + dy - 1, 0, H - 1);
#pragma unroll
            for (int dx = 0; dx < 3; ++dx) {
                int xc = iclamp(xx + dx - 1, 0, W - 1);
                in[ci * 9 + dy * 3 + dx] = x[ci * HW + yy * W + xc];
            }
        }
    ushort8 hv, mv, lv;
#pragma unroll
    for (int c8 = 0; c8 < 8; ++c8) {
        int co = coc * 8 + c8;
        float acc = b[co];
#pragma unroll
        for (int k = 0; k < 27; ++k) acc = fmaf(w[co * 27 + k], in[k], acc);
        float v = fmaxf(acc, 0.f);
        unsigned short h = f2bfu(v);
        float r1 = v - bf2f(h);
        unsigned short m = f2bfu(r1);
        unsigned short l = f2bfu(r1 - bf2f(m));
        hv[c8] = h; mv[c8] = m; lv[c8] = l;
    }
    *(ushort8*)(c1s + (long)p * 32 + coc * 8) = hv;
    *(ushort8*)(c1s + (long)32 * HW + (long)p * 32 + coc * 8) = mv;
    *(ushort8*)(c1s + (long)64 * HW + (long)p * 32 + coc * 8) = lv;
}

template <int P>
__device__ __forceinline__ void cls2_phase(const unsigned short* __restrict__ src,
                                           unsigned short* __restrict__ sh2,
                                           const unsigned short* __restrict__ wb,
                                           f32x4 acc[4][2], int tid, int ty, int tx) {
    int lane = tid & 63, wave = tid >> 6;
    int col = lane & 15, kq = lane >> 4;
    __syncthreads();
    for (int idx = tid; idx < 1296; idx += 256) {
        int pix = idx >> 2, g = idx & 3;
        int hy = iclamp(ty * 16 + pix / 18 - 1, 0, H - 1);
        int hx = iclamp(tx * 16 + pix % 18 - 1, 0, W - 1);
        ushort8 v = *(const ushort8*)(src + ((long)(hy * W + hx)) * 32 + g * 8);
        *(ushort8*)(sh2 + pix * 32 + ((g ^ ((pix >> 1) & 3)) * 8)) = v;
    }
    __syncthreads();
#pragma unroll
    for (int t = 0; t < 9; ++t) {
        int dy = t / 3, dx = t - dy * 3;
        short8 B[2][P];
#pragma unroll
        for (int nt = 0; nt < 2; ++nt)
#pragma unroll
            for (int pl = 0; pl < P; ++pl)
                B[nt][pl] = *(const short8*)(wb + ((pl * 9 + t) * 2 + nt) * 512 + lane * 8);
#pragma unroll
        for (int i = 0; i < 4; ++i) {
            int pix = (wave * 4 + i + dy) * 18 + col + dx;
            short8 a = *(const short8*)(sh2 + pix * 32 + ((kq ^ ((pix >> 1) & 3)) * 8));
#pragma unroll
            for (int nt = 0; nt < 2; ++nt)
#pragma unroll
                for (int pl = 0; pl < P; ++pl)
                    acc[i][nt] = __builtin_amdgcn_mfma_f32_16x16x32_bf16(a, B[nt][pl],
                                                                         acc[i][nt], 0, 0, 0);
        }
    }
}

__global__ __launch_bounds__(256, 2) void k_cls2m(const unsigned short* __restrict__ c1s,
                                                  const unsigned short* __restrict__ wpk,
                                                  const float* __restrict__ b2,
                                                  float* __restrict__ c2) {
    extern __shared__ unsigned short sh2[];
    int tid = threadIdx.x;
    int tile = blockIdx.x;  // 30 x 20
    int ty = tile / 20, tx = tile - ty * 20;
    int lane = tid & 63, wave = tid >> 6;
    int col = lane & 15, kq = lane >> 4;
    const unsigned short* wb = wpk + WQ_CLS2;
    f32x4 acc[4][2];
#pragma unroll
    for (int nt = 0; nt < 2; ++nt) {
        float bv = b2[nt * 16 + col];
#pragma unroll
        for (int i = 0; i < 4; ++i) acc[i][nt] = f32x4{bv, bv, bv, bv};
    }
    cls2_phase<3>(c1s, sh2, wb, acc, tid, ty, tx);
    cls2_phase<2>(c1s + (long)32 * HW, sh2, wb + 18 * 512, acc, tid, ty, tx);
    cls2_phase<1>(c1s + (long)64 * HW, sh2, wb + 36 * 512, acc, tid, ty, tx);
    __syncthreads();
    float* pool = (float*)sh2;  // [32co][257]
#pragma unroll
    for (int i = 0; i < 4; ++i)
#pragma unroll
        for (int nt = 0; nt < 2; ++nt)
#pragma unroll
            for (int rr = 0; rr < 4; ++rr)
                pool[(nt * 16 + col) * 257 + (wave * 4 + i) * 16 + kq * 4 + rr] =
                    fmaxf(acc[i][nt][rr], 0.f);
    __syncthreads();
#pragma unroll
    for (int k = 0; k < 8; ++k) {
        int o = tid + k * 256;
        int co = o >> 6, rem = o & 63;
        int py = rem >> 3, px = rem & 7;
        const float* lp = pool + co * 257 + py * 32 + px * 2;
        float m = fmaxf(fmaxf(lp[0], lp[1]), fmaxf(lp[16], lp[17]));
        c2[co * HW2 + (ty * 8 + py) * W2 + tx * 8 + px] = m;
    }
}

__global__ __launch_bounds__(256) void k_cls3(const float* __restrict__ in,
                                              const float* __restrict__ w,
                                              const float* __restrict__ b,
                                              float* __restrict__ p3) {
    int p = blockIdx.x * 256 + threadIdx.x;
    if (p >= HW2) return;
    int cc = blockIdx.y;  // 0..1
    int s = blockIdx.z;   // 0..1
    int y = p / W2, xx = p - y * W2;
    float acc[8];
#pragma unroll
    for (int co = 0; co < 8; ++co) acc[co] = s ? 0.f : b[cc * 8 + co];
    for (int cil = 0; cil < 16; ++cil) {
        int ci = s * 16 + cil;
        float v[9];
#pragma unroll
        for (int dy = 0; dy < 3; ++dy) {
            int yy = iclamp(y + dy - 1, 0, H2 - 1);
#pragma unroll
            for (int dx = 0; dx < 3; ++dx) {
                int xc = iclamp(xx + dx - 1, 0, W2 - 1);
                v[dy * 3 + dx] = in[ci * HW2 + yy * W2 + xc];
            }
        }
#pragma unroll
        for (int co = 0; co < 8; ++co)
#pragma unroll
            for (int k = 0; k < 9; ++k)
                acc[co] = fmaf(w[(cc * 8 + co) * 288 + ci * 9 + k], v[k], acc[co]);
    }
#pragma unroll
    for (int co = 0; co < 8; ++co) p3[(s * 16 + cc * 8 + co) * HW2 + p] = acc[co];
}

__global__ __launch_bounds__(256) void k_cls4f(const float* __restrict__ p3,
                                               const float* __restrict__ w,
                                               const float* __restrict__ b,
                                               float* __restrict__ out) {
    __shared__ float lds[8 * 256];
    int t = threadIdx.x;
    int tile = blockIdx.x;           // 15 x 10 tiles
    int ty = tile / 10, tx = tile - ty * 10;
    int ly = t >> 4, lx = t & 15;
    int y = ty * 16 + ly, xx = tx * 16 + lx;
    float acc[8];
#pragma unroll
    for (int co = 0; co < 8; ++co) acc[co] = b[co];
    for (int ci = 0; ci < 16; ++ci) {
        float v[9];
#pragma unroll
        for (int dy = 0; dy < 3; ++dy) {
            int yy = iclamp(y + dy - 1, 0, H2 - 1);
#pragma unroll
            for (int dx = 0; dx < 3; ++dx) {
                int xc = iclamp(xx + dx - 1, 0, W2 - 1);
                int idx = ci * HW2 + yy * W2 + xc;
                v[dy * 3 + dx] = fmaxf(p3[idx] + p3[idx + 16 * HW2], 0.f);
            }
        }
#pragma unroll
        for (int co = 0; co < 8; ++co) {
            const float* wp = w + co * 144 + ci * 9;
#pragma unroll
            for (int k = 0; k < 9; ++k) acc[co] = fmaf(wp[k], v[k], acc[co]);
        }
    }
#pragma unroll
    for (int co = 0; co < 8; ++co) lds[co * 256 + t] = fmaxf(acc[co], 0.f);
    __syncthreads();
#pragma unroll
    for (int k = 0; k < 2; ++k) {
        int o = t + k * 256;
        int co = o >> 6, rem = o & 63;
        int py = rem >> 3, px = rem & 7;
        const float* lp = lds + co * 256 + py * 32 + px * 2;
        float m = fmaxf(fmaxf(lp[0], lp[1]), fmaxf(lp[16], lp[17]));
        out[co * HW4 + (ty * 8 + py) * W4 + tx * 8 + px] = m;
    }
}

// conv 8->1, 5x5, stride 5; one wave per output block; shuffle-reduce.
__global__ __launch_bounds__(64) void k_cls5(const float* __restrict__ in,
                                             const float* __restrict__ w,
                                             const float* __restrict__ b,
                                             float* __restrict__ clsv,
                                             float* __restrict__ out_cls) {
    int bidx = blockIdx.x;  // 0..383
    int oy = bidx / NW, ox = bidx - oy * NW;
    int lane = threadIdx.x;
    float s = 0.f;
    for (int k = lane; k < 200; k += 64) {
        int ci = k / 25, r = k - ci * 25;
        int ky = r / 5, kx = r - ky * 5;
        s = fmaf(w[k], in[ci * HW4 + (oy * 5 + ky) * W4 + (ox * 5 + kx)], s);
    }
#pragma unroll
    for (int off = 32; off; off >>= 1) s += __shfl_down(s, off, 64);
    if (lane == 0) {
        float sig = 1.f / (1.f + expf(-(s + b[0])));
        clsv[bidx] = sig;
        out_cls[bidx] = sig;
    }
}

// ---------------- fully fused block path ----------------
// 5 wgs x 4 out rows per block (crop keeps rows 6..25 only).
// LDS: T1 32768B + T2 24576B + XH 2040B = 59384B -> 2 wgs/CU.
// B-fragment loads coalesced (fragment-major wpk); tap loops fully unrolled.
// s_setprio(1) around MFMA compute loops (T5): the 2 independent wgs per CU
// sit at different phases, so priority lets the MFMA-feeding wave win arbitration.
__global__ __launch_bounds__(512)
__attribute__((amdgpu_waves_per_eu(4, 4)))
void k_block(const float* __restrict__ x,
             const unsigned short* __restrict__ wpk,
             const float* __restrict__ lt_b1,
             const float* __restrict__ cx_b1,
             const float* __restrict__ lt_b2,
             const float* __restrict__ cx_b2,
             const float* __restrict__ cx_b3,
             const float* __restrict__ clsv,
             float* __restrict__ out) {
    extern __shared__ unsigned short sh[];
    unsigned short* T1 = sh;            // 16384 shorts
    unsigned short* T2 = sh + 16384;    // 12288 shorts
    unsigned short* XH = sh + 28672;    // 1020 shorts
    int wg = blockIdx.x;
    int b = wg / 5, e = wg - b * 5;
    bool cx = clsv[b] > 0.5f;
    int bh = b / NW, bw = b - bh * NW;
    int base = 6 + 4 * e;               // output rows base..base+3 (6..25)
    int tid = threadIdx.x;
    int lane = tid & 63, wave = tid >> 6;  // 0..7
    int col = lane & 15, kq = lane >> 4;

    // ---- phase 0: stage x halo (+ zero lt T1 channel region) ----
    if (!cx) {
        ushort8 z = {0, 0, 0, 0, 0, 0, 0, 0};
        for (int i = tid; i < 1024; i += 512) *(ushort8*)(T1 + i * 8) = z;
    }
    if (tid < 340) {
        int xr = tid / 34, xcc = tid - xr * 34;
        int yg = bh * 20 + (base - 3 + xr) - 6;
        int xg = bw * 20 + (xcc - 1) - 6;
        bool ok = (unsigned)yg < (unsigned)H && (unsigned)xg < (unsigned)W;
#pragma unroll
        for (int ci = 0; ci < 3; ++ci)
            XH[ci * 340 + tid] = ok ? f2bfu(x[ci * HW + yg * W + xg])
                                    : (unsigned short)0;
    }
    __syncthreads();

    // ---- phase 1: conv1 via MFMA (8 T1 rows = 16 m-tiles) ----
    if (cx) {
        short8 Bf[4];
        float bv[4];
#pragma unroll
        for (int nt = 0; nt < 4; ++nt) {
            Bf[nt] = *(const short8*)(wpk + WQ_FCX + nt * 512 + lane * 8);
            bv[nt] = cx_b1[nt * 16 + col];
        }
        __builtin_amdgcn_s_setprio(1);
#pragma unroll
        for (int i = 0; i < 2; ++i) {
            int mt = wave + 8 * i;      // 0..15
            int tr = mt >> 1, xc0 = (mt & 1) << 4;
            short8 av;
#pragma unroll
            for (int j = 0; j < 8; ++j) {
                int k = kq * 8 + j;
                int kk = k < 27 ? k : 0;
                int ci = kk / 9, t = kk - ci * 9;
                int dy = t / 3, dx = t - dy * 3;
                unsigned short v = XH[ci * 340 + (tr + dy) * 34 + (xc0 + col + dx)];
                av[j] = (k < 27) ? (short)v : (short)0;
            }
#pragma unroll
            for (int nt = 0; nt < 4; ++nt) {
                f32x4 acc = {bv[nt], bv[nt], bv[nt], bv[nt]};
                acc = __builtin_amdgcn_mfma_f32_16x16x32_bf16(av, Bf[nt], acc, 0, 0, 0);
                int co = nt * 16 + col;
#pragma unroll
                for (int r = 0; r < 4; ++r) {
                    int p1 = mt * 16 + kq * 4 + r;  // row-major pixel in 8x32 tile
                    T1[p1 * 64 + (((co >> 3) ^ (p1 & 7)) << 3) + (co & 7)] =
                        f2bfu(fmaxf(acc[r], 0.f));
                }
            }
        }
        __builtin_amdgcn_s_setprio(0);
    } else {
        short8 Bf = *(const short8*)(wpk + WQ_FLT + lane * 8);
        float bv = lt_b1[col];
        __builtin_amdgcn_s_setprio(1);
#pragma unroll
        for (int i = 0; i < 2; ++i) {
            int mt = wave + 8 * i;
            int tr = mt >> 1, xc0 = (mt & 1) << 4;
            short8 av;
#pragma unroll
            for (int j = 0; j < 8; ++j) {
                int k = kq * 8 + j;
                int kk = k < 27 ? k : 0;
                int ci = kk / 9, t = kk - ci * 9;
                int dy = t / 3, dx = t - dy * 3;
                unsigned short v = XH[ci * 340 + (tr + dy) * 34 + (xc0 + col + dx)];
                av[j] = (k < 27) ? (short)v : (short)0;
            }
            f32x4 acc = {bv, bv, bv, bv};
            acc = __builtin_amdgcn_mfma_f32_16x16x32_bf16(av, Bf, acc, 0, 0, 0);
#pragma unroll
            for (int r = 0; r < 4; ++r) {
                int p1 = mt * 16 + kq * 4 + r;
                T1[p1 * 32 + (((col >> 3) ^ ((p1 >> 1) & 3)) << 3) + (col & 7)] =
                    f2bfu(fmaxf(acc[r], 0.f));
            }
        }
        __builtin_amdgcn_s_setprio(0);
    }
    __syncthreads();

    if (cx) {
        // ---- phase 2: conv2 64->64 (T1 -> T2), relu. 6 T2 rows = 12 m-tiles.
        {
            f32x4 acc[2][4];
#pragma unroll
            for (int nt = 0; nt < 4; ++nt) {
                float bv = cx_b2[nt * 16 + col];
#pragma unroll
                for (int i = 0; i < 2; ++i) acc[i][nt] = f32x4{bv, bv, bv, bv};
            }
            __builtin_amdgcn_s_setprio(1);
#pragma unroll
            for (int t = 0; t < 9; ++t) {
                int dy = t / 3, dx = t - dy * 3;
                short8 B[4][2];
#pragma unroll
                for (int nt = 0; nt < 4; ++nt)
#pragma unroll
                    for (int kc = 0; kc < 2; ++kc)
                        B[nt][kc] = *(const short8*)(wpk + WQ_CX2 +
                                                     ((t * 2 + kc) * 4 + nt) * 512 +
                                                     lane * 8);
#pragma unroll
                for (int i = 0; i < 2; ++i) {
                    int mt = wave + 8 * i;
                    if (mt >= 12) continue;
                    int tr = (mt >> 1) + dy;              // T1 tile row 0..7
                    int xs = ((mt & 1) << 4) + col + dx - 1;
                    bool xv = (unsigned)xs < 32u;
                    int xcl = xs < 0 ? 0 : (xs > 31 ? 31 : xs);
                    int p1 = tr * 32 + xcl;
#pragma unroll
                    for (int kc = 0; kc < 2; ++kc) {
                        int c = kc * 4 + kq;
                        short8 a = *(const short8*)(T1 + p1 * 64 + ((c ^ (p1 & 7)) << 3));
                        if (!xv) a = short8{0, 0, 0, 0, 0, 0, 0, 0};
#pragma unroll
                        for (int nt = 0; nt < 4; ++nt)
                            acc[i][nt] = __builtin_amdgcn_mfma_f32_16x16x32_bf16(
                                a, B[nt][kc], acc[i][nt], 0, 0, 0);
                    }
                }
            }
            __builtin_amdgcn_s_setprio(0);
#pragma unroll
            for (int i = 0; i < 2; ++i) {
                int mt = wave + 8 * i;
                if (mt >= 12) continue;
#pragma unroll
                for (int nt = 0; nt < 4; ++nt) {
                    int co = nt * 16 + col;
#pragma unroll
                    for (int r = 0; r < 4; ++r) {
                        int p2 = mt * 16 + kq * 4 + r;  // pixel in 6x32 tile
                        T2[p2 * 64 + (((co >> 3) ^ (p2 & 7)) << 3) + (co & 7)] =
                            f2bfu(fmaxf(acc[i][nt][r], 0.f));
                    }
                }
            }
        }
        __syncthreads();
        // ---- phase 3: conv3 64->48 (T2) + pixel-shuffle/crop/clip -> out.
        {
            int mt = wave;
            f32x4 acc[3];
#pragma unroll
            for (int nt = 0; nt < 3; ++nt) {
                float bv = cx_b3[nt * 16 + col];
                acc[nt] = f32x4{bv, bv, bv, bv};
            }
            __builtin_amdgcn_s_setprio(1);
#pragma unroll
            for (int t = 0; t < 9; ++t) {
                int dy = t / 3, dx = t - dy * 3;
                short8 B[3][2];
#pragma unroll
                for (int nt = 0; nt < 3; ++nt)
#pragma unroll
                    for (int kc = 0; kc < 2; ++kc)
                        B[nt][kc] = *(const short8*)(wpk + WQ_CX3 +
                                                     ((t * 2 + kc) * 3 + nt) * 512 +
                                                     lane * 8);
                int tr2 = (mt >> 1) + dy;                 // T2 tile row 0..5
                int xs = ((mt & 1) << 4) + col + dx - 1;
                bool xv = (unsigned)xs < 32u;
                int xcl = xs < 0 ? 0 : (xs > 31 ? 31 : xs);
                int p2 = tr2 * 32 + xcl;
#pragma unroll
                for (int kc = 0; kc < 2; ++kc) {
                    int c = kc * 4 + kq;
                    short8 a = *(const short8*)(T2 + p2 * 64 + ((c ^ (p2 & 7)) << 3));
                    if (!xv) a = short8{0, 0, 0, 0, 0, 0, 0, 0};
#pragma unroll
                    for (int nt = 0; nt < 3; ++nt)
                        acc[nt] = __builtin_amdgcn_mfma_f32_16x16x32_bf16(
                            a, B[nt][kc], acc[nt], 0, 0, 0);
                }
            }
            __builtin_amdgcn_s_setprio(0);
            int py = base + (mt >> 1);                    // 6..25
#pragma unroll
            for (int nt = 0; nt < 3; ++nt) {
                int co = nt * 16 + col;
                int ch = co >> 4, dy2 = (co >> 2) & 3, dx2 = co & 3;
#pragma unroll
                for (int r = 0; r < 4; ++r) {
                    int p = mt * 16 + kq * 4 + r;
                    int px = p & 31;
                    int s0 = px * 4 + dx2 - 24;
                    if ((unsigned)s0 < 80u) {
                        int r0 = py * 4 + dy2 - 24;       // always in [0,79]
                        float v = fminf(fmaxf(acc[nt][r], 0.f), 1.f);
                        out[ch * 2457600 + (bh * 80 + r0) * 1280 + bw * 80 + s0] = v;
                    }
                }
            }
        }
    } else {
        // ---- lt: conv2 16->48 (T1) + pixel-shuffle/crop/clip -> out ----
        int mt = wave;
        f32x4 acc[3];
#pragma unroll
        for (int nt = 0; nt < 3; ++nt) {
            float bv = lt_b2[nt * 16 + col];
            acc[nt] = f32x4{bv, bv, bv, bv};
        }
        __builtin_amdgcn_s_setprio(1);
#pragma unroll
        for (int t = 0; t < 9; ++t) {
            int dy = t / 3, dx = t - dy * 3;
            short8 B[3];
#pragma unroll
            for (int nt = 0; nt < 3; ++nt)
                B[nt] = *(const short8*)(wpk + WQ_LT2 + (t * 3 + nt) * 512 + lane * 8);
            int tr = (mt >> 1) + 1 + dy;                  // T1 tile row 1..6
            int xs = ((mt & 1) << 4) + col + dx - 1;
            bool xv = (unsigned)xs < 32u;
            int xcl = xs < 0 ? 0 : (xs > 31 ? 31 : xs);
            int p1 = tr * 32 + xcl;
            short8 a = *(const short8*)(T1 + p1 * 32 + ((kq ^ ((p1 >> 1) & 3)) << 3));
            if (!xv) a = short8{0, 0, 0, 0, 0, 0, 0, 0};
#pragma unroll
            for (int nt = 0; nt < 3; ++nt)
                acc[nt] = __builtin_amdgcn_mfma_f32_16x16x32_bf16(a, B[nt], acc[nt], 0, 0, 0);
        }
        __builtin_amdgcn_s_setprio(0);
        int py = base + (mt >> 1);
#pragma unroll
        for (int nt = 0; nt < 3; ++nt) {
            int co = nt * 16 + col;
            int ch = co >> 4, dy2 = (co >> 2) & 3, dx2 = co & 3;
#pragma unroll
            for (int r = 0; r < 4; ++r) {
                int p = mt * 16 + kq * 4 + r;
                int px = p & 31;
                int s0 = px * 4 + dx2 - 24;
                if ((unsigned)s0 < 80u) {
                    int r0 = py * 4 + dy2 - 24;
                    float v = fminf(fmaxf(acc[nt][r], 0.f), 1.f);
                    out[ch * 2457600 + (bh * 80 + r0) * 1280 + bw * 80 + s0] = v;
                }
            }
        }
    }
}

extern "C" void kernel_launch(void* const* d_in, const int* in_sizes, int n_in,
                              void* d_out, int out_size, void* d_ws, size_t ws_size,
                              hipStream_t stream) {
    const float* x      = (const float*)d_in[0];
    const float* cls_w1 = (const float*)d_in[1];
    const float* cls_b1 = (const float*)d_in[2];
    const float* cls_w2 = (const float*)d_in[3];
    const float* cls_b2 = (const float*)d_in[4];
    const float* cls_w3 = (const float*)d_in[5];
    const float* cls_b3 = (const float*)d_in[6];
    const float* cls_w4 = (const float*)d_in[7];
    const float* cls_b4 = (const float*)d_in[8];
    const float* cls_w5 = (const float*)d_in[9];
    const float* cls_b5 = (const float*)d_in[10];
    const float* lt_w1  = (const float*)d_in[11];
    const float* lt_b1  = (const float*)d_in[12];
    const float* lt_w2  = (const float*)d_in[13];
    const float* lt_b2  = (const float*)d_in[14];
    const float* cx_w1  = (const float*)d_in[15];
    const float* cx_b1  = (const float*)d_in[16];
    const float* cx_w2  = (const float*)d_in[17];
    const float* cx_b2  = (const float*)d_in[18];
    const float* cx_w3  = (const float*)d_in[19];
    const float* cx_b3  = (const float*)d_in[20];

    float* ws = (float*)d_ws;
    float* out = (float*)d_out;

    // persistent small buffers
    size_t off = 0;
    float* c2 = ws + off;   off += (size_t)32 * HW2;
    float* c4 = ws + off;   off += (size_t)8 * HW4;
    float* clsv = ws + off; off += 384;
    unsigned short* wpk = (unsigned short*)(ws + off); off += (WPK_ALL + 1) / 2;
    size_t fixed = off;

    // scratch: c1 split planes + p3 (classifier phase only)
    unsigned short* c1s = (unsigned short*)(ws + fixed);   // 96*HW shorts
    float* p3 = ws + fixed + (size_t)48 * HW;              // 32*HW2 floats

    (void)hipFuncSetAttribute((const void*)k_cls2m,
                              hipFuncAttributeMaxDynamicSharedMemorySize, 32896);
    (void)hipFuncSetAttribute((const void*)k_block,
                              hipFuncAttributeMaxDynamicSharedMemorySize, 59384);

    k_pack<<<(WPK_ALL + 255) / 256, 256, 0, stream>>>(cx_w2, cx_w3, lt_w2, cx_w1, lt_w1,
                                                      cls_w2, wpk);
    k_cls1s<<<dim3((HW + 255) / 256, 4), 256, 0, stream>>>(x, cls_w1, cls_b1, c1s);
    k_cls2m<<<600, 256, 32896, stream>>>(c1s, wpk, cls_b2, c2);
    k_cls3<<<dim3(150, 2, 2), 256, 0, stream>>>(c2, cls_w3, cls_b3, p3);
    k_cls4f<<<150, 256, 0, stream>>>(p3, cls_w4, cls_b4, c4);
    k_cls5<<<NB, 64, 0, stream>>>(c4, cls_w5, cls_b5, clsv, out + IMG_PIX);
    k_block<<<NB * 5, 512, 59384, stream>>>(x, wpk, lt_b1, cx_b1, lt_b2, cx_b2,
                                            cx_b3, clsv, out);
}

// Round 20
// 169.516 us; speedup vs baseline: 1.0391x; 1.0391x over previous
//
#include <hip/hip_runtime.h>
#include <hip/hip_bf16.h>
#include <math.h>

static constexpr int H = 480, W = 320, NH = 24, NW = 16, NB = 384;
static constexpr int HW = H * W;            // 153600
static constexpr int H2 = 240, W2 = 160;
static constexpr int HW2 = H2 * W2;         // 38400
static constexpr int H4 = 120, W4 = 80;
static constexpr int HW4 = H4 * W4;         // 9600
static constexpr int IMG_PIX = 3 * 1920 * 1280;  // 7372800

typedef __attribute__((ext_vector_type(8))) short short8;
typedef __attribute__((ext_vector_type(4))) float f32x4;
typedef __attribute__((ext_vector_type(8))) unsigned short ushort8;

// fragment-major packed weights: each chunk = 512 shorts = [lane(64)][8],
// lane = (kq<<4)|col holds w[co = nt*16+col][ci = kc*32 + kq*8 + j].
// A wave's B-fragment load is ONE contiguous 1KB read (16 cache lines).
static constexpr int WQ_CX2 = 0;          // 72 chunks: (t*2+kc)*4+nt
static constexpr int WQ_CX3 = 36864;      // 54 chunks: (t*2+kc)*3+nt
static constexpr int WQ_LT2 = 64512;      // 27 chunks: t*3+nt (ci>=16 zero)
static constexpr int WQ_FCX = 78336;      // 4 chunks: nt (k>=27 zero)
static constexpr int WQ_FLT = 80384;      // 1 chunk
static constexpr int WQ_CLS2 = 80896;     // 54 chunks: (pl*9+t)*2+nt
static constexpr int WPK_ALL = 108544;

__device__ __forceinline__ int iclamp(int v, int lo, int hi) {
    return v < lo ? lo : (v > hi ? hi : v);
}
__device__ __forceinline__ unsigned short f2bfu(float x) {
    __hip_bfloat16 h = __float2bfloat16(x);
    return *reinterpret_cast<unsigned short*>(&h);
}
__device__ __forceinline__ float bf2f(unsigned short u) {
    __hip_bfloat16 h = *reinterpret_cast<__hip_bfloat16*>(&u);
    return __bfloat162float(h);
}

// ---------------- fused prep: cls1 (split planes) + weight pre-pack ----------------
// Blocks 0..2399: conv1 3->32 edge pad + relu, output h/m/l split-bf16 planes
//   (block = coc*600 + pblk, coc in 0..3).
// Blocks 2400..2823: fragment-major weight pack (424 blocks x 256 = WPK_ALL+pad).
// The two halves are mutually independent; fusing removes one serial dispatch.
__global__ __launch_bounds__(256) void k_prep(const float* __restrict__ x,
                                              const float* __restrict__ cls_w1,
                                              const float* __restrict__ cls_b1,
                                              const float* __restrict__ cx_w2,
                                              const float* __restrict__ cx_w3,
                                              const float* __restrict__ lt_w2,
                                              const float* __restrict__ cx_w1,
                                              const float* __restrict__ lt_w1,
                                              const float* __restrict__ cls_w2,
                                              unsigned short* __restrict__ c1s,
                                              unsigned short* __restrict__ wpk) {
    int blk = blockIdx.x;
    if (blk < 2400) {
        int coc = blk / 600;
        int p = (blk - coc * 600) * 256 + threadIdx.x;
        if (p >= HW) return;
        int y = p / W, xx = p - y * W;
        float in[27];
#pragma unroll
        for (int ci = 0; ci < 3; ++ci)
#pragma unroll
            for (int dy = 0; dy < 3; ++dy) {
                int yy = iclamp(y + dy - 1, 0, H - 1);
#pragma unroll
                for (int dx = 0; dx < 3; ++dx) {
                    int xc = iclamp(xx + dx - 1, 0, W - 1);
                    in[ci * 9 + dy * 3 + dx] = x[ci * HW + yy * W + xc];
                }
            }
        ushort8 hv, mv, lv;
#pragma unroll
        for (int c8 = 0; c8 < 8; ++c8) {
            int co = coc * 8 + c8;
            float acc = cls_b1[co];
#pragma unroll
            for (int k = 0; k < 27; ++k) acc = fmaf(cls_w1[co * 27 + k], in[k], acc);
            float v = fmaxf(acc, 0.f);
            unsigned short h = f2bfu(v);
            float r1 = v - bf2f(h);
            unsigned short m = f2bfu(r1);
            unsigned short l = f2bfu(r1 - bf2f(m));
            hv[c8] = h; mv[c8] = m; lv[c8] = l;
        }
        *(ushort8*)(c1s + (long)p * 32 + coc * 8) = hv;
        *(ushort8*)(c1s + (long)32 * HW + (long)p * 32 + coc * 8) = mv;
        *(ushort8*)(c1s + (long)64 * HW + (long)p * 32 + coc * 8) = lv;
        return;
    }
    int i = (blk - 2400) * 256 + threadIdx.x;
    if (i >= WPK_ALL) return;
    float v = 0.f;
    if (i < WQ_CX3) {
        int c = i >> 9, r = i & 511;
        int lane = r >> 3, j = r & 7;
        int col = lane & 15, kq = lane >> 4;
        int nt = c & 3, kc = (c >> 2) & 1, t = c >> 3;
        int co = nt * 16 + col, ci = kc * 32 + kq * 8 + j;
        v = cx_w2[(co * 64 + ci) * 9 + t];
    } else if (i < WQ_LT2) {
        int c = (i - WQ_CX3) >> 9, r = i & 511;
        int lane = r >> 3, j = r & 7;
        int col = lane & 15, kq = lane >> 4;
        int nt = c % 3, q = c / 3;
        int kc = q & 1, t = q >> 1;
        int co = nt * 16 + col, ci = kc * 32 + kq * 8 + j;
        v = cx_w3[(co * 64 + ci) * 9 + t];
    } else if (i < WQ_FCX) {
        int c = (i - WQ_LT2) >> 9, r = i & 511;
        int lane = r >> 3, j = r & 7;
        int col = lane & 15, kq = lane >> 4;
        int nt = c % 3, t = c / 3;
        int co = nt * 16 + col, ci = kq * 8 + j;
        v = (ci < 16) ? lt_w2[(co * 16 + ci) * 9 + t] : 0.f;
    } else if (i < WQ_FLT) {
        int c = (i - WQ_FCX) >> 9, r = i & 511;
        int lane = r >> 3, j = r & 7;
        int col = lane & 15, kq = lane >> 4;
        int co = c * 16 + col, k = kq * 8 + j;
        v = (k < 27) ? cx_w1[co * 27 + k] : 0.f;
    } else if (i < WQ_CLS2) {
        int r = i & 511;
        int lane = r >> 3, j = r & 7;
        int col = lane & 15, kq = lane >> 4;
        int k = kq * 8 + j;
        v = (k < 27) ? lt_w1[col * 27 + k] : 0.f;
    } else {
        int c = (i - WQ_CLS2) >> 9, r = i & 511;
        int lane = r >> 3, j = r & 7;
        int col = lane & 15, kq = lane >> 4;
        int nt = c & 1, q = c >> 1;
        int t = q % 9, pl = q / 9;
        int co = nt * 16 + col, ci = kq * 8 + j;
        float w = cls_w2[(co * 32 + ci) * 9 + t];
        unsigned short h = f2bfu(w);
        float r1 = w - bf2f(h);
        unsigned short m = f2bfu(r1);
        unsigned short l = f2bfu(r1 - bf2f(m));
        wpk[i] = pl == 0 ? h : (pl == 1 ? m : l);
        return;
    }
    wpk[i] = f2bfu(v);
}

// ---------------- classifier ----------------

template <int P>
__device__ __forceinline__ void cls2_phase(const unsigned short* __restrict__ src,
                                           unsigned short* __restrict__ sh2,
                                           const unsigned short* __restrict__ wb,
                                           f32x4 acc[4][2], int tid, int ty, int tx) {
    int lane = tid & 63, wave = tid >> 6;
    int col = lane & 15, kq = lane >> 4;
    __syncthreads();
    for (int idx = tid; idx < 1296; idx += 256) {
        int pix = idx >> 2, g = idx & 3;
        int hy = iclamp(ty * 16 + pix / 18 - 1, 0, H - 1);
        int hx = iclamp(tx * 16 + pix % 18 - 1, 0, W - 1);
        ushort8 v = *(const ushort8*)(src + ((long)(hy * W + hx)) * 32 + g * 8);
        *(ushort8*)(sh2 + pix * 32 + ((g ^ ((pix >> 1) & 3)) * 8)) = v;
    }
    __syncthreads();
#pragma unroll
    for (int t = 0; t < 9; ++t) {
        int dy = t / 3, dx = t - dy * 3;
        short8 B[2][P];
#pragma unroll
        for (int nt = 0; nt < 2; ++nt)
#pragma unroll
            for (int pl = 0; pl < P; ++pl)
                B[nt][pl] = *(const short8*)(wb + ((pl * 9 + t) * 2 + nt) * 512 + lane * 8);
#pragma unroll
        for (int i = 0; i < 4; ++i) {
            int pix = (wave * 4 + i + dy) * 18 + col + dx;
            short8 a = *(const short8*)(sh2 + pix * 32 + ((kq ^ ((pix >> 1) & 3)) * 8));
#pragma unroll
            for (int nt = 0; nt < 2; ++nt)
#pragma unroll
                for (int pl = 0; pl < P; ++pl)
                    acc[i][nt] = __builtin_amdgcn_mfma_f32_16x16x32_bf16(a, B[nt][pl],
                                                                         acc[i][nt], 0, 0, 0);
        }
    }
}

__global__ __launch_bounds__(256, 2) void k_cls2m(const unsigned short* __restrict__ c1s,
                                                  const unsigned short* __restrict__ wpk,
                                                  const float* __restrict__ b2,
                                                  float* __restrict__ c2) {
    extern __shared__ unsigned short sh2[];
    int tid = threadIdx.x;
    int tile = blockIdx.x;  // 30 x 20
    int ty = tile / 20, tx = tile - ty * 20;
    int lane = tid & 63, wave = tid >> 6;
    int col = lane & 15, kq = lane >> 4;
    const unsigned short* wb = wpk + WQ_CLS2;
    f32x4 acc[4][2];
#pragma unroll
    for (int nt = 0; nt < 2; ++nt) {
        float bv = b2[nt * 16 + col];
#pragma unroll
        for (int i = 0; i < 4; ++i) acc[i][nt] = f32x4{bv, bv, bv, bv};
    }
    cls2_phase<3>(c1s, sh2, wb, acc, tid, ty, tx);
    cls2_phase<2>(c1s + (long)32 * HW, sh2, wb + 18 * 512, acc, tid, ty, tx);
    cls2_phase<1>(c1s + (long)64 * HW, sh2, wb + 36 * 512, acc, tid, ty, tx);
    __syncthreads();
    float* pool = (float*)sh2;  // [32co][257]
#pragma unroll
    for (int i = 0; i < 4; ++i)
#pragma unroll
        for (int nt = 0; nt < 2; ++nt)
#pragma unroll
            for (int rr = 0; rr < 4; ++rr)
                pool[(nt * 16 + col) * 257 + (wave * 4 + i) * 16 + kq * 4 + rr] =
                    fmaxf(acc[i][nt][rr], 0.f);
    __syncthreads();
#pragma unroll
    for (int k = 0; k < 8; ++k) {
        int o = tid + k * 256;
        int co = o >> 6, rem = o & 63;
        int py = rem >> 3, px = rem & 7;
        const float* lp = pool + co * 257 + py * 32 + px * 2;
        float m = fmaxf(fmaxf(lp[0], lp[1]), fmaxf(lp[16], lp[17]));
        c2[co * HW2 + (ty * 8 + py) * W2 + tx * 8 + px] = m;
    }
}

__global__ __launch_bounds__(256) void k_cls3(const float* __restrict__ in,
                                              const float* __restrict__ w,
                                              const float* __restrict__ b,
                                              float* __restrict__ p3) {
    int p = blockIdx.x * 256 + threadIdx.x;
    if (p >= HW2) return;
    int cc = blockIdx.y;  // 0..1
    int s = blockIdx.z;   // 0..1
    int y = p / W2, xx = p - y * W2;
    float acc[8];
#pragma unroll
    for (int co = 0; co < 8; ++co) acc[co] = s ? 0.f : b[cc * 8 + co];
    for (int cil = 0; cil < 16; ++cil) {
        int ci = s * 16 + cil;
        float v[9];
#pragma unroll
        for (int dy = 0; dy < 3; ++dy) {
            int yy = iclamp(y + dy - 1, 0, H2 - 1);
#pragma unroll
            for (int dx = 0; dx < 3; ++dx) {
                int xc = iclamp(xx + dx - 1, 0, W2 - 1);
                v[dy * 3 + dx] = in[ci * HW2 + yy * W2 + xc];
            }
        }
#pragma unroll
        for (int co = 0; co < 8; ++co)
#pragma unroll
            for (int k = 0; k < 9; ++k)
                acc[co] = fmaf(w[(cc * 8 + co) * 288 + ci * 9 + k], v[k], acc[co]);
    }
#pragma unroll
    for (int co = 0; co < 8; ++co) p3[(s * 16 + cc * 8 + co) * HW2 + p] = acc[co];
}

__global__ __launch_bounds__(256) void k_cls4f(const float* __restrict__ p3,
                                               const float* __restrict__ w,
                                               const float* __restrict__ b,
                                               float* __restrict__ out) {
    __shared__ float lds[8 * 256];
    int t = threadIdx.x;
    int tile = blockIdx.x;           // 15 x 10 tiles
    int ty = tile / 10, tx = tile - ty * 10;
    int ly = t >> 4, lx = t & 15;
    int y = ty * 16 + ly, xx = tx * 16 + lx;
    float acc[8];
#pragma unroll
    for (int co = 0; co < 8; ++co) acc[co] = b[co];
    for (int ci = 0; ci < 16; ++ci) {
        float v[9];
#pragma unroll
        for (int dy = 0; dy < 3; ++dy) {
            int yy = iclamp(y + dy - 1, 0, H2 - 1);
#pragma unroll
            for (int dx = 0; dx < 3; ++dx) {
                int xc = iclamp(xx + dx - 1, 0, W2 - 1);
                int idx = ci * HW2 + yy * W2 + xc;
                v[dy * 3 + dx] = fmaxf(p3[idx] + p3[idx + 16 * HW2], 0.f);
            }
        }
#pragma unroll
        for (int co = 0; co < 8; ++co) {
            const float* wp = w + co * 144 + ci * 9;
#pragma unroll
            for (int k = 0; k < 9; ++k) acc[co] = fmaf(wp[k], v[k], acc[co]);
        }
    }
#pragma unroll
    for (int co = 0; co < 8; ++co) lds[co * 256 + t] = fmaxf(acc[co], 0.f);
    __syncthreads();
#pragma unroll
    for (int k = 0; k < 2; ++k) {
        int o = t + k * 256;
        int co = o >> 6, rem = o & 63;
        int py = rem >> 3, px = rem & 7;
        const float* lp = lds + co * 256 + py * 32 + px * 2;
        float m = fmaxf(fmaxf(lp[0], lp[1]), fmaxf(lp[16], lp[17]));
        out[co * HW4 + (ty * 8 + py) * W4 + tx * 8 + px] = m;
    }
}

// conv 8->1, 5x5, stride 5; one wave per output block; shuffle-reduce.
__global__ __launch_bounds__(64) void k_cls5(const float* __restrict__ in,
                                             const float* __restrict__ w,
                                             const float* __restrict__ b,
                                             float* __restrict__ clsv,
                                             float* __restrict__ out_cls) {
    int bidx = blockIdx.x;  // 0..383
    int oy = bidx / NW, ox = bidx - oy * NW;
    int lane = threadIdx.x;
    float s = 0.f;
    for (int k = lane; k < 200; k += 64) {
        int ci = k / 25, r = k - ci * 25;
        int ky = r / 5, kx = r - ky * 5;
        s = fmaf(w[k], in[ci * HW4 + (oy * 5 + ky) * W4 + (ox * 5 + kx)], s);
    }
#pragma unroll
    for (int off = 32; off; off >>= 1) s += __shfl_down(s, off, 64);
    if (lane == 0) {
        float sig = 1.f / (1.f + expf(-(s + b[0])));
        clsv[bidx] = sig;
        out_cls[bidx] = sig;
    }
}

// ---------------- fully fused block path ----------------
// 5 wgs x 4 out rows per block (crop keeps rows 6..25 only).
// LDS: T1 32768B + T2 24576B + XH 2040B = 59384B -> 2 wgs/CU.
// B-fragment loads coalesced (fragment-major wpk); tap loops fully unrolled.
// Measured config space: 8-row/2-row tiles, 1024 threads, setprio -> all
// null or worse; this 4-row/512-thread layout is the measured optimum.
__global__ __launch_bounds__(512)
__attribute__((amdgpu_waves_per_eu(4, 4)))
void k_block(const float* __restrict__ x,
             const unsigned short* __restrict__ wpk,
             const float* __restrict__ lt_b1,
             const float* __restrict__ cx_b1,
             const float* __restrict__ lt_b2,
             const float* __restrict__ cx_b2,
             const float* __restrict__ cx_b3,
             const float* __restrict__ clsv,
             float* __restrict__ out) {
    extern __shared__ unsigned short sh[];
    unsigned short* T1 = sh;            // 16384 shorts
    unsigned short* T2 = sh + 16384;    // 12288 shorts
    unsigned short* XH = sh + 28672;    // 1020 shorts
    int wg = blockIdx.x;
    int b = wg / 5, e = wg - b * 5;
    bool cx = clsv[b] > 0.5f;
    int bh = b / NW, bw = b - bh * NW;
    int base = 6 + 4 * e;               // output rows base..base+3 (6..25)
    int tid = threadIdx.x;
    int lane = tid & 63, wave = tid >> 6;  // 0..7
    int col = lane & 15, kq = lane >> 4;

    // ---- phase 0: stage x halo (+ zero lt T1 channel region) ----
    if (!cx) {
        ushort8 z = {0, 0, 0, 0, 0, 0, 0, 0};
        for (int i = tid; i < 1024; i += 512) *(ushort8*)(T1 + i * 8) = z;
    }
    if (tid < 340) {
        int xr = tid / 34, xcc = tid - xr * 34;
        int yg = bh * 20 + (base - 3 + xr) - 6;
        int xg = bw * 20 + (xcc - 1) - 6;
        bool ok = (unsigned)yg < (unsigned)H && (unsigned)xg < (unsigned)W;
#pragma unroll
        for (int ci = 0; ci < 3; ++ci)
            XH[ci * 340 + tid] = ok ? f2bfu(x[ci * HW + yg * W + xg])
                                    : (unsigned short)0;
    }
    __syncthreads();

    // ---- phase 1: conv1 via MFMA (8 T1 rows = 16 m-tiles) ----
    if (cx) {
        short8 Bf[4];
        float bv[4];
#pragma unroll
        for (int nt = 0; nt < 4; ++nt) {
            Bf[nt] = *(const short8*)(wpk + WQ_FCX + nt * 512 + lane * 8);
            bv[nt] = cx_b1[nt * 16 + col];
        }
#pragma unroll
        for (int i = 0; i < 2; ++i) {
            int mt = wave + 8 * i;      // 0..15
            int tr = mt >> 1, xc0 = (mt & 1) << 4;
            short8 av;
#pragma unroll
            for (int j = 0; j < 8; ++j) {
                int k = kq * 8 + j;
                int kk = k < 27 ? k : 0;
                int ci = kk / 9, t = kk - ci * 9;
                int dy = t / 3, dx = t - dy * 3;
                unsigned short v = XH[ci * 340 + (tr + dy) * 34 + (xc0 + col + dx)];
                av[j] = (k < 27) ? (short)v : (short)0;
            }
#pragma unroll
            for (int nt = 0; nt < 4; ++nt) {
                f32x4 acc = {bv[nt], bv[nt], bv[nt], bv[nt]};
                acc = __builtin_amdgcn_mfma_f32_16x16x32_bf16(av, Bf[nt], acc, 0, 0, 0);
                int co = nt * 16 + col;
#pragma unroll
                for (int r = 0; r < 4; ++r) {
                    int p1 = mt * 16 + kq * 4 + r;  // row-major pixel in 8x32 tile
                    T1[p1 * 64 + (((co >> 3) ^ (p1 & 7)) << 3) + (co & 7)] =
                        f2bfu(fmaxf(acc[r], 0.f));
                }
            }
        }
    } else {
        short8 Bf = *(const short8*)(wpk + WQ_FLT + lane * 8);
        float bv = lt_b1[col];
#pragma unroll
        for (int i = 0; i < 2; ++i) {
            int mt = wave + 8 * i;
            int tr = mt >> 1, xc0 = (mt & 1) << 4;
            short8 av;
#pragma unroll
            for (int j = 0; j < 8; ++j) {
                int k = kq * 8 + j;
                int kk = k < 27 ? k : 0;
                int ci = kk / 9, t = kk - ci * 9;
                int dy = t / 3, dx = t - dy * 3;
                unsigned short v = XH[ci * 340 + (tr + dy) * 34 + (xc0 + col + dx)];
                av[j] = (k < 27) ? (short)v : (short)0;
            }
            f32x4 acc = {bv, bv, bv, bv};
            acc = __builtin_amdgcn_mfma_f32_16x16x32_bf16(av, Bf, acc, 0, 0, 0);
#pragma unroll
            for (int r = 0; r < 4; ++r) {
                int p1 = mt * 16 + kq * 4 + r;
                T1[p1 * 32 + (((col >> 3) ^ ((p1 >> 1) & 3)) << 3) + (col & 7)] =
                    f2bfu(fmaxf(acc[r], 0.f));
            }
        }
    }
    __syncthreads();

    if (cx) {
        // ---- phase 2: conv2 64->64 (T1 -> T2), relu. 6 T2 rows = 12 m-tiles.
        {
            f32x4 acc[2][4];
#pragma unroll
            for (int nt = 0; nt < 4; ++nt) {
                float bv = cx_b2[nt * 16 + col];
#pragma unroll
                for (int i = 0; i < 2; ++i) acc[i][nt] = f32x4{bv, bv, bv, bv};
            }
#pragma unroll
            for (int t = 0; t < 9; ++t) {
                int dy = t / 3, dx = t - dy * 3;
                short8 B[4][2];
#pragma unroll
                for (int nt = 0; nt < 4; ++nt)
#pragma unroll
                    for (int kc = 0; kc < 2; ++kc)
                        B[nt][kc] = *(const short8*)(wpk + WQ_CX2 +
                                                     ((t * 2 + kc) * 4 + nt) * 512 +
                                                     lane * 8);
#pragma unroll
                for (int i = 0; i < 2; ++i) {
                    int mt = wave + 8 * i;
                    if (mt >= 12) continue;
                    int tr = (mt >> 1) + dy;              // T1 tile row 0..7
                    int xs = ((mt & 1) << 4) + col + dx - 1;
                    bool xv = (unsigned)xs < 32u;
                    int xcl = xs < 0 ? 0 : (xs > 31 ? 31 : xs);
                    int p1 = tr * 32 + xcl;
#pragma unroll
                    for (int kc = 0; kc < 2; ++kc) {
                        int c = kc * 4 + kq;
                        short8 a = *(const short8*)(T1 + p1 * 64 + ((c ^ (p1 & 7)) << 3));
                        if (!xv) a = short8{0, 0, 0, 0, 0, 0, 0, 0};
#pragma unroll
                        for (int nt = 0; nt < 4; ++nt)
                            acc[i][nt] = __builtin_amdgcn_mfma_f32_16x16x32_bf16(
                                a, B[nt][kc], acc[i][nt], 0, 0, 0);
                    }
                }
            }
#pragma unroll
            for (int i = 0; i < 2; ++i) {
                int mt = wave + 8 * i;
                if (mt >= 12) continue;
#pragma unroll
                for (int nt = 0; nt < 4; ++nt) {
                    int co = nt * 16 + col;
#pragma unroll
                    for (int r = 0; r < 4; ++r) {
                        int p2 = mt * 16 + kq * 4 + r;  // pixel in 6x32 tile
                        T2[p2 * 64 + (((co >> 3) ^ (p2 & 7)) << 3) + (co & 7)] =
                            f2bfu(fmaxf(acc[i][nt][r], 0.f));
                    }
                }
            }
        }
        __syncthreads();
        // ---- phase 3: conv3 64->48 (T2) + pixel-shuffle/crop/clip -> out.
        {
            int mt = wave;
            f32x4 acc[3];
#pragma unroll
            for (int nt = 0; nt < 3; ++nt) {
                float bv = cx_b3[nt * 16 + col];
                acc[nt] = f32x4{bv, bv, bv, bv};
            }
#pragma unroll
            for (int t = 0; t < 9; ++t) {
                int dy = t / 3, dx = t - dy * 3;
                short8 B[3][2];
#pragma unroll
                for (int nt = 0; nt < 3; ++nt)
#pragma unroll
                    for (int kc = 0; kc < 2; ++kc)
                        B[nt][kc] = *(const short8*)(wpk + WQ_CX3 +
                                                     ((t * 2 + kc) * 3 + nt) * 512 +
                                                     lane * 8);
                int tr2 = (mt >> 1) + dy;                 // T2 tile row 0..5
                int xs = ((mt & 1) << 4) + col + dx - 1;
                bool xv = (unsigned)xs < 32u;
                int xcl = xs < 0 ? 0 : (xs > 31 ? 31 : xs);
                int p2 = tr2 * 32 + xcl;
#pragma unroll
                for (int kc = 0; kc < 2; ++kc) {
                    int c = kc * 4 + kq;
                    short8 a = *(const short8*)(T2 + p2 * 64 + ((c ^ (p2 & 7)) << 3));
                    if (!xv) a = short8{0, 0, 0, 0, 0, 0, 0, 0};
#pragma unroll
                    for (int nt = 0; nt < 3; ++nt)
                        acc[nt] = __builtin_amdgcn_mfma_f32_16x16x32_bf16(
                            a, B[nt][kc], acc[nt], 0, 0, 0);
                }
            }
            int py = base + (mt >> 1);                    // 6..25
#pragma unroll
            for (int nt = 0; nt < 3; ++nt) {
                int co = nt * 16 + col;
                int ch = co >> 4, dy2 = (co >> 2) & 3, dx2 = co & 3;
#pragma unroll
                for (int r = 0; r < 4; ++r) {
                    int p = mt * 16 + kq * 4 + r;
                    int px = p & 31;
                    int s0 = px * 4 + dx2 - 24;
                    if ((unsigned)s0 < 80u) {
                        int r0 = py * 4 + dy2 - 24;       // always in [0,79]
                        float v = fminf(fmaxf(acc[nt][r], 0.f), 1.f);
                        out[ch * 2457600 + (bh * 80 + r0) * 1280 + bw * 80 + s0] = v;
                    }
                }
            }
        }
    } else {
        // ---- lt: conv2 16->48 (T1) + pixel-shuffle/crop/clip -> out ----
        int mt = wave;
        f32x4 acc[3];
#pragma unroll
        for (int nt = 0; nt < 3; ++nt) {
            float bv = lt_b2[nt * 16 + col];
            acc[nt] = f32x4{bv, bv, bv, bv};
        }
#pragma unroll
        for (int t = 0; t < 9; ++t) {
            int dy = t / 3, dx = t - dy * 3;
            short8 B[3];
#pragma unroll
            for (int nt = 0; nt < 3; ++nt)
                B[nt] = *(const short8*)(wpk + WQ_LT2 + (t * 3 + nt) * 512 + lane * 8);
            int tr = (mt >> 1) + 1 + dy;                  // T1 tile row 1..6
            int xs = ((mt & 1) << 4) + col + dx - 1;
            bool xv = (unsigned)xs < 32u;
            int xcl = xs < 0 ? 0 : (xs > 31 ? 31 : xs);
            int p1 = tr * 32 + xcl;
            short8 a = *(const short8*)(T1 + p1 * 32 + ((kq ^ ((p1 >> 1) & 3)) << 3));
            if (!xv) a = short8{0, 0, 0, 0, 0, 0, 0, 0};
#pragma unroll
            for (int nt = 0; nt < 3; ++nt)
                acc[nt] = __builtin_amdgcn_mfma_f32_16x16x32_bf16(a, B[nt], acc[nt], 0, 0, 0);
        }
        int py = base + (mt >> 1);
#pragma unroll
        for (int nt = 0; nt < 3; ++nt) {
            int co = nt * 16 + col;
            int ch = co >> 4, dy2 = (co >> 2) & 3, dx2 = co & 3;
#pragma unroll
            for (int r = 0; r < 4; ++r) {
                int p = mt * 16 + kq * 4 + r;
                int px = p & 31;
                int s0 = px * 4 + dx2 - 24;
                if ((unsigned)s0 < 80u) {
                    int r0 = py * 4 + dy2 - 24;
                    float v = fminf(fmaxf(acc[nt][r], 0.f), 1.f);
                    out[ch * 2457600 + (bh * 80 + r0) * 1280 + bw * 80 + s0] = v;
                }
            }
        }
    }
}

extern "C" void kernel_launch(void* const* d_in, const int* in_sizes, int n_in,
                              void* d_out, int out_size, void* d_ws, size_t ws_size,
                              hipStream_t stream) {
    const float* x      = (const float*)d_in[0];
    const float* cls_w1 = (const float*)d_in[1];
    const float* cls_b1 = (const float*)d_in[2];
    const float* cls_w2 = (const float*)d_in[3];
    const float* cls_b2 = (const float*)d_in[4];
    const float* cls_w3 = (const float*)d_in[5];
    const float* cls_b3 = (const float*)d_in[6];
    const float* cls_w4 = (const float*)d_in[7];
    const float* cls_b4 = (const float*)d_in[8];
    const float* cls_w5 = (const float*)d_in[9];
    const float* cls_b5 = (const float*)d_in[10];
    const float* lt_w1  = (const float*)d_in[11];
    const float* lt_b1  = (const float*)d_in[12];
    const float* lt_w2  = (const float*)d_in[13];
    const float* lt_b2  = (const float*)d_in[14];
    const float* cx_w1  = (const float*)d_in[15];
    const float* cx_b1  = (const float*)d_in[16];
    const float* cx_w2  = (const float*)d_in[17];
    const float* cx_b2  = (const float*)d_in[18];
    const float* cx_w3  = (const float*)d_in[19];
    const float* cx_b3  = (const float*)d_in[20];

    float* ws = (float*)d_ws;
    float* out = (float*)d_out;

    // persistent small buffers
    size_t off = 0;
    float* c2 = ws + off;   off += (size_t)32 * HW2;
    float* c4 = ws + off;   off += (size_t)8 * HW4;
    float* clsv = ws + off; off += 384;
    unsigned short* wpk = (unsigned short*)(ws + off); off += (WPK_ALL + 1) / 2;
    size_t fixed = off;

    // scratch: c1 split planes + p3 (classifier phase only)
    unsigned short* c1s = (unsigned short*)(ws + fixed);   // 96*HW shorts
    float* p3 = ws + fixed + (size_t)48 * HW;              // 32*HW2 floats

    (void)hipFuncSetAttribute((const void*)k_cls2m,
                              hipFuncAttributeMaxDynamicSharedMemorySize, 32896);
    (void)hipFuncSetAttribute((const void*)k_block,
                              hipFuncAttributeMaxDynamicSharedMemorySize, 59384);

    k_prep<<<2400 + (WPK_ALL + 255) / 256, 256, 0, stream>>>(
        x, cls_w1, cls_b1, cx_w2, cx_w3, lt_w2, cx_w1, lt_w1, cls_w2, c1s, wpk);
    k_cls2m<<<600, 256, 32896, stream>>>(c1s, wpk, cls_b2, c2);
    k_cls3<<<dim3(150, 2, 2), 256, 0, stream>>>(c2, cls_w3, cls_b3, p3);
    k_cls4f<<<150, 256, 0, stream>>>(p3, cls_w4, cls_b4, c4);
    k_cls5<<<NB, 64, 0, stream>>>(c4, cls_w5, cls_b5, clsv, out + IMG_PIX);
    k_block<<<NB * 5, 512, 59384, stream>>>(x, wpk, lt_b1, cx_b1, lt_b2, cx_b2,
                                            cx_b3, clsv, out);
}

// Round 21
// 153.588 us; speedup vs baseline: 1.1468x; 1.1037x over previous
//
#include <hip/hip_runtime.h>
#include <hip/hip_bf16.h>
#include <math.h>

static constexpr int H = 480, W = 320, NH = 24, NW = 16, NB = 384;
static constexpr int HW = H * W;            // 153600
static constexpr int H2 = 240, W2 = 160;
static constexpr int HW2 = H2 * W2;         // 38400
static constexpr int H4 = 120, W4 = 80;
static constexpr int HW4 = H4 * W4;         // 9600
static constexpr int IMG_PIX = 3 * 1920 * 1280;  // 7372800

typedef __attribute__((ext_vector_type(8))) short short8;
typedef __attribute__((ext_vector_type(4))) float f32x4;
typedef __attribute__((ext_vector_type(8))) unsigned short ushort8;

// fragment-major packed weights: each chunk = 512 shorts = [lane(64)][8],
// lane = (kq<<4)|col holds w[co = nt*16+col][ci = kc*32 + kq*8 + j].
// Chunks for one tap are contiguous (phase2: 8/t, phase3: 6/t, lt: 3/t).
static constexpr int WQ_CX2 = 0;          // 72 chunks: (t*2+kc)*4+nt
static constexpr int WQ_CX3 = 36864;      // 54 chunks: (t*2+kc)*3+nt
static constexpr int WQ_LT2 = 64512;      // 27 chunks: t*3+nt (ci>=16 zero)
static constexpr int WQ_FCX = 78336;      // 4 chunks: nt (k>=27 zero)
static constexpr int WQ_FLT = 80384;      // 1 chunk
static constexpr int WQ_CLS2 = 80896;     // 54 chunks: (pl*9+t)*2+nt
static constexpr int WPK_ALL = 108544;

__device__ __forceinline__ int iclamp(int v, int lo, int hi) {
    return v < lo ? lo : (v > hi ? hi : v);
}
__device__ __forceinline__ unsigned short f2bfu(float x) {
    __hip_bfloat16 h = __float2bfloat16(x);
    return *reinterpret_cast<unsigned short*>(&h);
}
__device__ __forceinline__ float bf2f(unsigned short u) {
    __hip_bfloat16 h = *reinterpret_cast<__hip_bfloat16*>(&u);
    return __bfloat162float(h);
}

// ---------------- fused prep: cls1 (split planes) + weight pre-pack ----------------
__global__ __launch_bounds__(256) void k_prep(const float* __restrict__ x,
                                              const float* __restrict__ cls_w1,
                                              const float* __restrict__ cls_b1,
                                              const float* __restrict__ cx_w2,
                                              const float* __restrict__ cx_w3,
                                              const float* __restrict__ lt_w2,
                                              const float* __restrict__ cx_w1,
                                              const float* __restrict__ lt_w1,
                                              const float* __restrict__ cls_w2,
                                              unsigned short* __restrict__ c1s,
                                              unsigned short* __restrict__ wpk) {
    int blk = blockIdx.x;
    if (blk < 2400) {
        int coc = blk / 600;
        int p = (blk - coc * 600) * 256 + threadIdx.x;
        if (p >= HW) return;
        int y = p / W, xx = p - y * W;
        float in[27];
#pragma unroll
        for (int ci = 0; ci < 3; ++ci)
#pragma unroll
            for (int dy = 0; dy < 3; ++dy) {
                int yy = iclamp(y + dy - 1, 0, H - 1);
#pragma unroll
                for (int dx = 0; dx < 3; ++dx) {
                    int xc = iclamp(xx + dx - 1, 0, W - 1);
                    in[ci * 9 + dy * 3 + dx] = x[ci * HW + yy * W + xc];
                }
            }
        ushort8 hv, mv, lv;
#pragma unroll
        for (int c8 = 0; c8 < 8; ++c8) {
            int co = coc * 8 + c8;
            float acc = cls_b1[co];
#pragma unroll
            for (int k = 0; k < 27; ++k) acc = fmaf(cls_w1[co * 27 + k], in[k], acc);
            float v = fmaxf(acc, 0.f);
            unsigned short h = f2bfu(v);
            float r1 = v - bf2f(h);
            unsigned short m = f2bfu(r1);
            unsigned short l = f2bfu(r1 - bf2f(m));
            hv[c8] = h; mv[c8] = m; lv[c8] = l;
        }
        *(ushort8*)(c1s + (long)p * 32 + coc * 8) = hv;
        *(ushort8*)(c1s + (long)32 * HW + (long)p * 32 + coc * 8) = mv;
        *(ushort8*)(c1s + (long)64 * HW + (long)p * 32 + coc * 8) = lv;
        return;
    }
    int i = (blk - 2400) * 256 + threadIdx.x;
    if (i >= WPK_ALL) return;
    float v = 0.f;
    if (i < WQ_CX3) {
        int c = i >> 9, r = i & 511;
        int lane = r >> 3, j = r & 7;
        int col = lane & 15, kq = lane >> 4;
        int nt = c & 3, kc = (c >> 2) & 1, t = c >> 3;
        int co = nt * 16 + col, ci = kc * 32 + kq * 8 + j;
        v = cx_w2[(co * 64 + ci) * 9 + t];
    } else if (i < WQ_LT2) {
        int c = (i - WQ_CX3) >> 9, r = i & 511;
        int lane = r >> 3, j = r & 7;
        int col = lane & 15, kq = lane >> 4;
        int nt = c % 3, q = c / 3;
        int kc = q & 1, t = q >> 1;
        int co = nt * 16 + col, ci = kc * 32 + kq * 8 + j;
        v = cx_w3[(co * 64 + ci) * 9 + t];
    } else if (i < WQ_FCX) {
        int c = (i - WQ_LT2) >> 9, r = i & 511;
        int lane = r >> 3, j = r & 7;
        int col = lane & 15, kq = lane >> 4;
        int nt = c % 3, t = c / 3;
        int co = nt * 16 + col, ci = kq * 8 + j;
        v = (ci < 16) ? lt_w2[(co * 16 + ci) * 9 + t] : 0.f;
    } else if (i < WQ_FLT) {
        int c = (i - WQ_FCX) >> 9, r = i & 511;
        int lane = r >> 3, j = r & 7;
        int col = lane & 15, kq = lane >> 4;
        int co = c * 16 + col, k = kq * 8 + j;
        v = (k < 27) ? cx_w1[co * 27 + k] : 0.f;
    } else if (i < WQ_CLS2) {
        int r = i & 511;
        int lane = r >> 3, j = r & 7;
        int col = lane & 15, kq = lane >> 4;
        int k = kq * 8 + j;
        v = (k < 27) ? lt_w1[col * 27 + k] : 0.f;
    } else {
        int c = (i - WQ_CLS2) >> 9, r = i & 511;
        int lane = r >> 3, j = r & 7;
        int col = lane & 15, kq = lane >> 4;
        int nt = c & 1, q = c >> 1;
        int t = q % 9, pl = q / 9;
        int co = nt * 16 + col, ci = kq * 8 + j;
        float w = cls_w2[(co * 32 + ci) * 9 + t];
        unsigned short h = f2bfu(w);
        float r1 = w - bf2f(h);
        unsigned short m = f2bfu(r1);
        unsigned short l = f2bfu(r1 - bf2f(m));
        wpk[i] = pl == 0 ? h : (pl == 1 ? m : l);
        return;
    }
    wpk[i] = f2bfu(v);
}

// ---------------- classifier ----------------

template <int P>
__device__ __forceinline__ void cls2_phase(const unsigned short* __restrict__ src,
                                           unsigned short* __restrict__ sh2,
                                           const unsigned short* __restrict__ wb,
                                           f32x4 acc[4][2], int tid, int ty, int tx) {
    int lane = tid & 63, wave = tid >> 6;
    int col = lane & 15, kq = lane >> 4;
    __syncthreads();
    for (int idx = tid; idx < 1296; idx += 256) {
        int pix = idx >> 2, g = idx & 3;
        int hy = iclamp(ty * 16 + pix / 18 - 1, 0, H - 1);
        int hx = iclamp(tx * 16 + pix % 18 - 1, 0, W - 1);
        ushort8 v = *(const ushort8*)(src + ((long)(hy * W + hx)) * 32 + g * 8);
        *(ushort8*)(sh2 + pix * 32 + ((g ^ ((pix >> 1) & 3)) * 8)) = v;
    }
    __syncthreads();
#pragma unroll
    for (int t = 0; t < 9; ++t) {
        int dy = t / 3, dx = t - dy * 3;
        short8 B[2][P];
#pragma unroll
        for (int nt = 0; nt < 2; ++nt)
#pragma unroll
            for (int pl = 0; pl < P; ++pl)
                B[nt][pl] = *(const short8*)(wb + ((pl * 9 + t) * 2 + nt) * 512 + lane * 8);
#pragma unroll
        for (int i = 0; i < 4; ++i) {
            int pix = (wave * 4 + i + dy) * 18 + col + dx;
            short8 a = *(const short8*)(sh2 + pix * 32 + ((kq ^ ((pix >> 1) & 3)) * 8));
#pragma unroll
            for (int nt = 0; nt < 2; ++nt)
#pragma unroll
                for (int pl = 0; pl < P; ++pl)
                    acc[i][nt] = __builtin_amdgcn_mfma_f32_16x16x32_bf16(a, B[nt][pl],
                                                                         acc[i][nt], 0, 0, 0);
        }
    }
}

__global__ __launch_bounds__(256, 2) void k_cls2m(const unsigned short* __restrict__ c1s,
                                                  const unsigned short* __restrict__ wpk,
                                                  const float* __restrict__ b2,
                                                  float* __restrict__ c2) {
    extern __shared__ unsigned short sh2[];
    int tid = threadIdx.x;
    int tile = blockIdx.x;  // 30 x 20
    int ty = tile / 20, tx = tile - ty * 20;
    int lane = tid & 63, wave = tid >> 6;
    int col = lane & 15, kq = lane >> 4;
    const unsigned short* wb = wpk + WQ_CLS2;
    f32x4 acc[4][2];
#pragma unroll
    for (int nt = 0; nt < 2; ++nt) {
        float bv = b2[nt * 16 + col];
#pragma unroll
        for (int i = 0; i < 4; ++i) acc[i][nt] = f32x4{bv, bv, bv, bv};
    }
    cls2_phase<3>(c1s, sh2, wb, acc, tid, ty, tx);
    cls2_phase<2>(c1s + (long)32 * HW, sh2, wb + 18 * 512, acc, tid, ty, tx);
    cls2_phase<1>(c1s + (long)64 * HW, sh2, wb + 36 * 512, acc, tid, ty, tx);
    __syncthreads();
    float* pool = (float*)sh2;  // [32co][257]
#pragma unroll
    for (int i = 0; i < 4; ++i)
#pragma unroll
        for (int nt = 0; nt < 2; ++nt)
#pragma unroll
            for (int rr = 0; rr < 4; ++rr)
                pool[(nt * 16 + col) * 257 + (wave * 4 + i) * 16 + kq * 4 + rr] =
                    fmaxf(acc[i][nt][rr], 0.f);
    __syncthreads();
#pragma unroll
    for (int k = 0; k < 8; ++k) {
        int o = tid + k * 256;
        int co = o >> 6, rem = o & 63;
        int py = rem >> 3, px = rem & 7;
        const float* lp = pool + co * 257 + py * 32 + px * 2;
        float m = fmaxf(fmaxf(lp[0], lp[1]), fmaxf(lp[16], lp[17]));
        c2[co * HW2 + (ty * 8 + py) * W2 + tx * 8 + px] = m;
    }
}

__global__ __launch_bounds__(256) void k_cls3(const float* __restrict__ in,
                                              const float* __restrict__ w,
                                              const float* __restrict__ b,
                                              float* __restrict__ p3) {
    int p = blockIdx.x * 256 + threadIdx.x;
    if (p >= HW2) return;
    int cc = blockIdx.y;  // 0..1
    int s = blockIdx.z;   // 0..1
    int y = p / W2, xx = p - y * W2;
    float acc[8];
#pragma unroll
    for (int co = 0; co < 8; ++co) acc[co] = s ? 0.f : b[cc * 8 + co];
    for (int cil = 0; cil < 16; ++cil) {
        int ci = s * 16 + cil;
        float v[9];
#pragma unroll
        for (int dy = 0; dy < 3; ++dy) {
            int yy = iclamp(y + dy - 1, 0, H2 - 1);
#pragma unroll
            for (int dx = 0; dx < 3; ++dx) {
                int xc = iclamp(xx + dx - 1, 0, W2 - 1);
                v[dy * 3 + dx] = in[ci * HW2 + yy * W2 + xc];
            }
        }
#pragma unroll
        for (int co = 0; co < 8; ++co)
#pragma unroll
            for (int k = 0; k < 9; ++k)
                acc[co] = fmaf(w[(cc * 8 + co) * 288 + ci * 9 + k], v[k], acc[co]);
    }
#pragma unroll
    for (int co = 0; co < 8; ++co) p3[(s * 16 + cc * 8 + co) * HW2 + p] = acc[co];
}

__global__ __launch_bounds__(256) void k_cls4f(const float* __restrict__ p3,
                                               const float* __restrict__ w,
                                               const float* __restrict__ b,
                                               float* __restrict__ out) {
    __shared__ float lds[8 * 256];
    int t = threadIdx.x;
    int tile = blockIdx.x;           // 15 x 10 tiles
    int ty = tile / 10, tx = tile - ty * 10;
    int ly = t >> 4, lx = t & 15;
    int y = ty * 16 + ly, xx = tx * 16 + lx;
    float acc[8];
#pragma unroll
    for (int co = 0; co < 8; ++co) acc[co] = b[co];
    for (int ci = 0; ci < 16; ++ci) {
        float v[9];
#pragma unroll
        for (int dy = 0; dy < 3; ++dy) {
            int yy = iclamp(y + dy - 1, 0, H2 - 1);
#pragma unroll
            for (int dx = 0; dx < 3; ++dx) {
                int xc = iclamp(xx + dx - 1, 0, W2 - 1);
                int idx = ci * HW2 + yy * W2 + xc;
                v[dy * 3 + dx] = fmaxf(p3[idx] + p3[idx + 16 * HW2], 0.f);
            }
        }
#pragma unroll
        for (int co = 0; co < 8; ++co) {
            const float* wp = w + co * 144 + ci * 9;
#pragma unroll
            for (int k = 0; k < 9; ++k) acc[co] = fmaf(wp[k], v[k], acc[co]);
        }
    }
#pragma unroll
    for (int co = 0; co < 8; ++co) lds[co * 256 + t] = fmaxf(acc[co], 0.f);
    __syncthreads();
#pragma unroll
    for (int k = 0; k < 2; ++k) {
        int o = t + k * 256;
        int co = o >> 6, rem = o & 63;
        int py = rem >> 3, px = rem & 7;
        const float* lp = lds + co * 256 + py * 32 + px * 2;
        float m = fmaxf(fmaxf(lp[0], lp[1]), fmaxf(lp[16], lp[17]));
        out[co * HW4 + (ty * 8 + py) * W4 + tx * 8 + px] = m;
    }
}

// conv 8->1, 5x5, stride 5; one wave per output block; shuffle-reduce.
__global__ __launch_bounds__(64) void k_cls5(const float* __restrict__ in,
                                             const float* __restrict__ w,
                                             const float* __restrict__ b,
                                             float* __restrict__ clsv,
                                             float* __restrict__ out_cls) {
    int bidx = blockIdx.x;  // 0..383
    int oy = bidx / NW, ox = bidx - oy * NW;
    int lane = threadIdx.x;
    float s = 0.f;
    for (int k = lane; k < 200; k += 64) {
        int ci = k / 25, r = k - ci * 25;
        int ky = r / 5, kx = r - ky * 5;
        s = fmaf(w[k], in[ci * HW4 + (oy * 5 + ky) * W4 + (ox * 5 + kx)], s);
    }
#pragma unroll
    for (int off = 32; off; off >>= 1) s += __shfl_down(s, off, 64);
    if (lane == 0) {
        float sig = 1.f / (1.f + expf(-(s + b[0])));
        clsv[bidx] = sig;
        out_cls[bidx] = sig;
    }
}

// ---------------- fully fused block path ----------------
// 5 wgs x 4 out rows per block (crop keeps rows 6..25 only).
// LDS: T1 32768B + T2 24576B + XH 2040B (+pad) + WB 16384B = 75776B -> 2 wgs/CU.
// Per-tap B double-buffer (T14 issue-early/write-late): B staged cooperatively
// into LDS once per wg instead of per wave -> 8x less L2 B-traffic.
__global__ __launch_bounds__(512)
__attribute__((amdgpu_waves_per_eu(4, 4)))
void k_block(const float* __restrict__ x,
             const unsigned short* __restrict__ wpk,
             const float* __restrict__ lt_b1,
             const float* __restrict__ cx_b1,
             const float* __restrict__ lt_b2,
             const float* __restrict__ cx_b2,
             const float* __restrict__ cx_b3,
             const float* __restrict__ clsv,
             float* __restrict__ out) {
    extern __shared__ unsigned short sh[];
    unsigned short* T1 = sh;            // 16384 shorts
    unsigned short* T2 = sh + 16384;    // 12288 shorts
    unsigned short* XH = sh + 28672;    // 1020 shorts (pad to 29696)
    unsigned short* WB = sh + 29696;    // 8192 shorts (2 x 4096 halves)
    int wg = blockIdx.x;
    int b = wg / 5, e = wg - b * 5;
    bool cx = clsv[b] > 0.5f;
    int bh = b / NW, bw = b - bh * NW;
    int base = 6 + 4 * e;               // output rows base..base+3 (6..25)
    int tid = threadIdx.x;
    int lane = tid & 63, wave = tid >> 6;  // 0..7
    int col = lane & 15, kq = lane >> 4;

    // ---- phase 0: stage x halo (+ zero lt T1 channel region) ----
    if (!cx) {
        ushort8 z = {0, 0, 0, 0, 0, 0, 0, 0};
        for (int i = tid; i < 1024; i += 512) *(ushort8*)(T1 + i * 8) = z;
    }
    if (tid < 340) {
        int xr = tid / 34, xcc = tid - xr * 34;
        int yg = bh * 20 + (base - 3 + xr) - 6;
        int xg = bw * 20 + (xcc - 1) - 6;
        bool ok = (unsigned)yg < (unsigned)H && (unsigned)xg < (unsigned)W;
#pragma unroll
        for (int ci = 0; ci < 3; ++ci)
            XH[ci * 340 + tid] = ok ? f2bfu(x[ci * HW + yg * W + xg])
                                    : (unsigned short)0;
    }
    __syncthreads();

    // ---- phase 1: conv1 via MFMA (8 T1 rows = 16 m-tiles) ----
    if (cx) {
        short8 Bf[4];
        float bv[4];
#pragma unroll
        for (int nt = 0; nt < 4; ++nt) {
            Bf[nt] = *(const short8*)(wpk + WQ_FCX + nt * 512 + lane * 8);
            bv[nt] = cx_b1[nt * 16 + col];
        }
#pragma unroll
        for (int i = 0; i < 2; ++i) {
            int mt = wave + 8 * i;      // 0..15
            int tr = mt >> 1, xc0 = (mt & 1) << 4;
            short8 av;
#pragma unroll
            for (int j = 0; j < 8; ++j) {
                int k = kq * 8 + j;
                int kk = k < 27 ? k : 0;
                int ci = kk / 9, t = kk - ci * 9;
                int dy = t / 3, dx = t - dy * 3;
                unsigned short v = XH[ci * 340 + (tr + dy) * 34 + (xc0 + col + dx)];
                av[j] = (k < 27) ? (short)v : (short)0;
            }
#pragma unroll
            for (int nt = 0; nt < 4; ++nt) {
                f32x4 acc = {bv[nt], bv[nt], bv[nt], bv[nt]};
                acc = __builtin_amdgcn_mfma_f32_16x16x32_bf16(av, Bf[nt], acc, 0, 0, 0);
                int co = nt * 16 + col;
#pragma unroll
                for (int r = 0; r < 4; ++r) {
                    int p1 = mt * 16 + kq * 4 + r;  // row-major pixel in 8x32 tile
                    T1[p1 * 64 + (((co >> 3) ^ (p1 & 7)) << 3) + (co & 7)] =
                        f2bfu(fmaxf(acc[r], 0.f));
                }
            }
        }
        // stage phase-2 tap0 B into WB half 0 (8KB, all 512 threads)
        {
            ushort8 nb0 = *(const ushort8*)(wpk + WQ_CX2 + tid * 8);
            *(ushort8*)(WB + tid * 8) = nb0;
        }
    } else {
        short8 Bf = *(const short8*)(wpk + WQ_FLT + lane * 8);
        float bv = lt_b1[col];
#pragma unroll
        for (int i = 0; i < 2; ++i) {
            int mt = wave + 8 * i;
            int tr = mt >> 1, xc0 = (mt & 1) << 4;
            short8 av;
#pragma unroll
            for (int j = 0; j < 8; ++j) {
                int k = kq * 8 + j;
                int kk = k < 27 ? k : 0;
                int ci = kk / 9, t = kk - ci * 9;
                int dy = t / 3, dx = t - dy * 3;
                unsigned short v = XH[ci * 340 + (tr + dy) * 34 + (xc0 + col + dx)];
                av[j] = (k < 27) ? (short)v : (short)0;
            }
            f32x4 acc = {bv, bv, bv, bv};
            acc = __builtin_amdgcn_mfma_f32_16x16x32_bf16(av, Bf, acc, 0, 0, 0);
#pragma unroll
            for (int r = 0; r < 4; ++r) {
                int p1 = mt * 16 + kq * 4 + r;
                T1[p1 * 32 + (((col >> 3) ^ ((p1 >> 1) & 3)) << 3) + (col & 7)] =
                    f2bfu(fmaxf(acc[r], 0.f));
            }
        }
        // stage lt conv2 tap0 B into WB half 0 (3KB, threads 0..191)
        if (tid < 192) {
            ushort8 nb0 = *(const ushort8*)(wpk + WQ_LT2 + tid * 8);
            *(ushort8*)(WB + tid * 8) = nb0;
        }
    }
    __syncthreads();

    if (cx) {
        // ---- phase 2: conv2 64->64 (T1 -> T2), relu. 6 T2 rows = 12 m-tiles.
        // B read from WB dbuf; next tap staged issue-early/write-late.
        {
            f32x4 acc[2][4];
#pragma unroll
            for (int nt = 0; nt < 4; ++nt) {
                float bv = cx_b2[nt * 16 + col];
#pragma unroll
                for (int i = 0; i < 2; ++i) acc[i][nt] = f32x4{bv, bv, bv, bv};
            }
#pragma unroll
            for (int t = 0; t < 9; ++t) {
                int dy = t / 3, dx = t - dy * 3;
                ushort8 nb;
                if (t < 8)
                    nb = *(const ushort8*)(wpk + WQ_CX2 + (t + 1) * 4096 + tid * 8);
                const unsigned short* WBc = WB + (t & 1) * 4096;
                short8 B[4][2];
#pragma unroll
                for (int nt = 0; nt < 4; ++nt)
#pragma unroll
                    for (int kc = 0; kc < 2; ++kc)
                        B[nt][kc] = *(const short8*)(WBc + (kc * 4 + nt) * 512 + lane * 8);
#pragma unroll
                for (int i = 0; i < 2; ++i) {
                    int mt = wave + 8 * i;
                    if (mt >= 12) continue;
                    int tr = (mt >> 1) + dy;              // T1 tile row 0..7
                    int xs = ((mt & 1) << 4) + col + dx - 1;
                    bool xv = (unsigned)xs < 32u;
                    int xcl = xs < 0 ? 0 : (xs > 31 ? 31 : xs);
                    int p1 = tr * 32 + xcl;
#pragma unroll
                    for (int kc = 0; kc < 2; ++kc) {
                        int c = kc * 4 + kq;
                        short8 a = *(const short8*)(T1 + p1 * 64 + ((c ^ (p1 & 7)) << 3));
                        if (!xv) a = short8{0, 0, 0, 0, 0, 0, 0, 0};
#pragma unroll
                        for (int nt = 0; nt < 4; ++nt)
                            acc[i][nt] = __builtin_amdgcn_mfma_f32_16x16x32_bf16(
                                a, B[nt][kc], acc[i][nt], 0, 0, 0);
                    }
                }
                if (t < 8)
                    *(ushort8*)(WB + ((t + 1) & 1) * 4096 + tid * 8) = nb;
                __syncthreads();
            }
#pragma unroll
            for (int i = 0; i < 2; ++i) {
                int mt = wave + 8 * i;
                if (mt >= 12) continue;
#pragma unroll
                for (int nt = 0; nt < 4; ++nt) {
                    int co = nt * 16 + col;
#pragma unroll
                    for (int r = 0; r < 4; ++r) {
                        int p2 = mt * 16 + kq * 4 + r;  // pixel in 6x32 tile
                        T2[p2 * 64 + (((co >> 3) ^ (p2 & 7)) << 3) + (co & 7)] =
                            f2bfu(fmaxf(acc[i][nt][r], 0.f));
                    }
                }
            }
            // stage phase-3 tap0 B (6KB, threads 0..383); half-0 reads fenced
            // by the tap-8 barrier above.
            if (tid < 384) {
                ushort8 nb0 = *(const ushort8*)(wpk + WQ_CX3 + tid * 8);
                *(ushort8*)(WB + tid * 8) = nb0;
            }
        }
        __syncthreads();
        // ---- phase 3: conv3 64->48 (T2) + pixel-shuffle/crop/clip -> out.
        {
            int mt = wave;
            f32x4 acc[3];
#pragma unroll
            for (int nt = 0; nt < 3; ++nt) {
                float bv = cx_b3[nt * 16 + col];
                acc[nt] = f32x4{bv, bv, bv, bv};
            }
#pragma unroll
            for (int t = 0; t < 9; ++t) {
                int dy = t / 3, dx = t - dy * 3;
                ushort8 nb;
                if (t < 8 && tid < 384)
                    nb = *(const ushort8*)(wpk + WQ_CX3 + (t + 1) * 3072 + tid * 8);
                const unsigned short* WBc = WB + (t & 1) * 4096;
                short8 B[3][2];
#pragma unroll
                for (int nt = 0; nt < 3; ++nt)
#pragma unroll
                    for (int kc = 0; kc < 2; ++kc)
                        B[nt][kc] = *(const short8*)(WBc + (kc * 3 + nt) * 512 + lane * 8);
                int tr2 = (mt >> 1) + dy;                 // T2 tile row 0..5
                int xs = ((mt & 1) << 4) + col + dx - 1;
                bool xv = (unsigned)xs < 32u;
                int xcl = xs < 0 ? 0 : (xs > 31 ? 31 : xs);
                int p2 = tr2 * 32 + xcl;
#pragma unroll
                for (int kc = 0; kc < 2; ++kc) {
                    int c = kc * 4 + kq;
                    short8 a = *(const short8*)(T2 + p2 * 64 + ((c ^ (p2 & 7)) << 3));
                    if (!xv) a = short8{0, 0, 0, 0, 0, 0, 0, 0};
#pragma unroll
                    for (int nt = 0; nt < 3; ++nt)
                        acc[nt] = __builtin_amdgcn_mfma_f32_16x16x32_bf16(
                            a, B[nt][kc], acc[nt], 0, 0, 0);
                }
                if (t < 8) {
                    if (tid < 384)
                        *(ushort8*)(WB + ((t + 1) & 1) * 4096 + tid * 8) = nb;
                    __syncthreads();
                }
            }
            int py = base + (mt >> 1);                    // 6..25
#pragma unroll
            for (int nt = 0; nt < 3; ++nt) {
                int co = nt * 16 + col;
                int ch = co >> 4, dy2 = (co >> 2) & 3, dx2 = co & 3;
#pragma unroll
                for (int r = 0; r < 4; ++r) {
                    int p = mt * 16 + kq * 4 + r;
                    int px = p & 31;
                    int s0 = px * 4 + dx2 - 24;
                    if ((unsigned)s0 < 80u) {
                        int r0 = py * 4 + dy2 - 24;       // always in [0,79]
                        float v = fminf(fmaxf(acc[nt][r], 0.f), 1.f);
                        out[ch * 2457600 + (bh * 80 + r0) * 1280 + bw * 80 + s0] = v;
                    }
                }
            }
        }
    } else {
        // ---- lt: conv2 16->48 (T1) + pixel-shuffle/crop/clip -> out ----
        int mt = wave;
        f32x4 acc[3];
#pragma unroll
        for (int nt = 0; nt < 3; ++nt) {
            float bv = lt_b2[nt * 16 + col];
            acc[nt] = f32x4{bv, bv, bv, bv};
        }
#pragma unroll
        for (int t = 0; t < 9; ++t) {
            int dy = t / 3, dx = t - dy * 3;
            ushort8 nb;
            if (t < 8 && tid < 192)
                nb = *(const ushort8*)(wpk + WQ_LT2 + (t + 1) * 1536 + tid * 8);
            const unsigned short* WBc = WB + (t & 1) * 4096;
            short8 B[3];
#pragma unroll
            for (int nt = 0; nt < 3; ++nt)
                B[nt] = *(const short8*)(WBc + nt * 512 + lane * 8);
            int tr = (mt >> 1) + 1 + dy;                  // T1 tile row 1..6
            int xs = ((mt & 1) << 4) + col + dx - 1;
            bool xv = (unsigned)xs < 32u;
            int xcl = xs < 0 ? 0 : (xs > 31 ? 31 : xs);
            int p1 = tr * 32 + xcl;
            short8 a = *(const short8*)(T1 + p1 * 32 + ((kq ^ ((p1 >> 1) & 3)) << 3));
            if (!xv) a = short8{0, 0, 0, 0, 0, 0, 0, 0};
#pragma unroll
            for (int nt = 0; nt < 3; ++nt)
                acc[nt] = __builtin_amdgcn_mfma_f32_16x16x32_bf16(a, B[nt], acc[nt], 0, 0, 0);
            if (t < 8) {
                if (tid < 192)
                    *(ushort8*)(WB + ((t + 1) & 1) * 4096 + tid * 8) = nb;
                __syncthreads();
            }
        }
        int py = base + (mt >> 1);
#pragma unroll
        for (int nt = 0; nt < 3; ++nt) {
            int co = nt * 16 + col;
            int ch = co >> 4, dy2 = (co >> 2) & 3, dx2 = co & 3;
#pragma unroll
            for (int r = 0; r < 4; ++r) {
                int p = mt * 16 + kq * 4 + r;
                int px = p & 31;
                int s0 = px * 4 + dx2 - 24;
                if ((unsigned)s0 < 80u) {
                    int r0 = py * 4 + dy2 - 24;
                    float v = fminf(fmaxf(acc[nt][r], 0.f), 1.f);
                    out[ch * 2457600 + (bh * 80 + r0) * 1280 + bw * 80 + s0] = v;
                }
            }
        }
    }
}

extern "C" void kernel_launch(void* const* d_in, const int* in_sizes, int n_in,
                              void* d_out, int out_size, void* d_ws, size_t ws_size,
                              hipStream_t stream) {
    const float* x      = (const float*)d_in[0];
    const float* cls_w1 = (const float*)d_in[1];
    const float* cls_b1 = (const float*)d_in[2];
    const float* cls_w2 = (const float*)d_in[3];
    const float* cls_b2 = (const float*)d_in[4];
    const float* cls_w3 = (const float*)d_in[5];
    const float* cls_b3 = (const float*)d_in[6];
    const float* cls_w4 = (const float*)d_in[7];
    const float* cls_b4 = (const float*)d_in[8];
    const float* cls_w5 = (const float*)d_in[9];
    const float* cls_b5 = (const float*)d_in[10];
    const float* lt_w1  = (const float*)d_in[11];
    const float* lt_b1  = (const float*)d_in[12];
    const float* lt_w2  = (const float*)d_in[13];
    const float* lt_b2  = (const float*)d_in[14];
    const float* cx_w1  = (const float*)d_in[15];
    const float* cx_b1  = (const float*)d_in[16];
    const float* cx_w2  = (const float*)d_in[17];
    const float* cx_b2  = (const float*)d_in[18];
    const float* cx_w3  = (const float*)d_in[19];
    const float* cx_b3  = (const float*)d_in[20];

    float* ws = (float*)d_ws;
    float* out = (float*)d_out;

    // persistent small buffers
    size_t off = 0;
    float* c2 = ws + off;   off += (size_t)32 * HW2;
    float* c4 = ws + off;   off += (size_t)8 * HW4;
    float* clsv = ws + off; off += 384;
    unsigned short* wpk = (unsigned short*)(ws + off); off += (WPK_ALL + 1) / 2;
    size_t fixed = off;

    // scratch: c1 split planes + p3 (classifier phase only)
    unsigned short* c1s = (unsigned short*)(ws + fixed);   // 96*HW shorts
    float* p3 = ws + fixed + (size_t)48 * HW;              // 32*HW2 floats

    (void)hipFuncSetAttribute((const void*)k_cls2m,
                              hipFuncAttributeMaxDynamicSharedMemorySize, 32896);
    (void)hipFuncSetAttribute((const void*)k_block,
                              hipFuncAttributeMaxDynamicSharedMemorySize, 75776);

    k_prep<<<2400 + (WPK_ALL + 255) / 256, 256, 0, stream>>>(
        x, cls_w1, cls_b1, cx_w2, cx_w3, lt_w2, cx_w1, lt_w1, cls_w2, c1s, wpk);
    k_cls2m<<<600, 256, 32896, stream>>>(c1s, wpk, cls_b2, c2);
    k_cls3<<<dim3(150, 2, 2), 256, 0, stream>>>(c2, cls_w3, cls_b3, p3);
    k_cls4f<<<150, 256, 0, stream>>>(p3, cls_w4, cls_b4, c4);
    k_cls5<<<NB, 64, 0, stream>>>(c4, cls_w5, cls_b5, clsv, out + IMG_PIX);
    k_block<<<NB * 5, 512, 75776, stream>>>(x, wpk, lt_b1, cx_b1, lt_b2, cx_b2,
                                            cx_b3, clsv, out);
}